// Round 7
// baseline (405.439 us; speedup 1.0000x reference)
//
#include <hip/hip_runtime.h>
#include <hip/hip_bf16.h>

// Problem constants
constexpr int Bsz = 2048;   // batch
constexpr int Iin = 6156;   // input features (= K = N of the big GEMM)
constexpr int IF  = 6159;   // I + O (fin_w row length)
constexpr int Kp  = 6208;   // K padded to multiple of 64 (97 * 64)
constexpr int NpW = 6272;   // w rows stored in ws (multiple of 128)
constexpr int NT  = Kp / 32;             // 194 K-tiles (BK=32)
constexpr int MT  = Bsz / 256;           // 8 M-tiles
constexpr int NTN = 25;                  // N-tiles of 256 (cols 6272..6399 virtual zeros)

typedef __attribute__((ext_vector_type(8))) short short8;
typedef __attribute__((ext_vector_type(4))) float f32x4;

#define AS1 __attribute__((address_space(1)))
#define AS3 __attribute__((address_space(3)))

__device__ __forceinline__ short f2bf(float f) {
    union { float f; unsigned u; } v; v.f = f;
    unsigned r = v.u + 0x7FFFu + ((v.u >> 16) & 1u);   // RNE
    return (short)(r >> 16);
}

__device__ __forceinline__ short8 pack8(float4 a, float4 b) {
    short8 r;
    r[0] = f2bf(a.x); r[1] = f2bf(a.y); r[2] = f2bf(a.z); r[3] = f2bf(a.w);
    r[4] = f2bf(b.x); r[5] = f2bf(b.y); r[6] = f2bf(b.z); r[7] = f2bf(b.w);
    return r;
}

__device__ __forceinline__ void stage_chunk(const short* src, const short* ldsbase) {
    __builtin_amdgcn_global_load_lds((const AS1 void*)src, (AS3 void*)ldsbase, 16, 0, 0);
}

// ---------------------------------------------------------------------------
// Kernel 1: linear path + bias; fully initializes d_out.
// ---------------------------------------------------------------------------
__global__ void linear_init_kernel(const float* __restrict__ x,
                                   const float* __restrict__ lin_w,
                                   const float* __restrict__ lin_b,
                                   const float* __restrict__ fin_w,
                                   const float* __restrict__ fin_b,
                                   float* __restrict__ out) {
    int wid  = threadIdx.x >> 6;
    int lane = threadIdx.x & 63;
    int b = blockIdx.x * 4 + wid;
    if (b >= Bsz) return;
    const float4* xr = (const float4*)(x + (size_t)b * Iin);
    const float4* w0 = (const float4*)(lin_w);
    const float4* w1 = (const float4*)(lin_w + Iin);
    const float4* w2 = (const float4*)(lin_w + 2 * Iin);
    float s0 = 0.f, s1 = 0.f, s2 = 0.f;
    for (int i = lane; i < Iin / 4; i += 64) {
        float4 xv = xr[i];
        float4 a0 = w0[i], a1 = w1[i], a2 = w2[i];
        s0 += xv.x * a0.x + xv.y * a0.y + xv.z * a0.z + xv.w * a0.w;
        s1 += xv.x * a1.x + xv.y * a1.y + xv.z * a1.z + xv.w * a1.w;
        s2 += xv.x * a2.x + xv.y * a2.y + xv.z * a2.z + xv.w * a2.w;
    }
    #pragma unroll
    for (int off = 1; off < 64; off <<= 1) {
        s0 += __shfl_xor(s0, off, 64);
        s1 += __shfl_xor(s1, off, 64);
        s2 += __shfl_xor(s2, off, 64);
    }
    if (lane == 0) {
        float l0 = s0 + lin_b[0], l1 = s1 + lin_b[1], l2 = s2 + lin_b[2];
        #pragma unroll
        for (int o = 0; o < 3; ++o) {
            out[b * 3 + o] = fin_b[o]
                + fin_w[(size_t)o * IF + 0] * l0
                + fin_w[(size_t)o * IF + 1] * l1
                + fin_w[(size_t)o * IF + 2] * l2;
        }
    }
}

// ---------------------------------------------------------------------------
// Kernel 2: f32 -> bf16 conversion, zero padding, + segment XOR swizzle for
// BK=32 rows: within each 4-slot (32-col) block, ws slot sub holds source
// segment sub ^ ((r>>1)&3).
// ---------------------------------------------------------------------------
__global__ void convert_kernel(const float* __restrict__ src,
                               short* __restrict__ dst,
                               int rows, int src_rows) {
    const int segs = Kp / 8;   // 776
    int total = rows * segs;
    for (int c = blockIdx.x * blockDim.x + threadIdx.x; c < total;
         c += gridDim.x * blockDim.x) {
        int r     = c / segs;
        int s_dst = c - r * segs;
        int blk   = s_dst >> 2;
        int sub   = s_dst & 3;
        int src_col = (blk << 5) + ((sub ^ ((r >> 1) & 3)) << 3);
        short8 st;
        if (r < src_rows && src_col + 8 <= Iin) {
            const float* s = src + (size_t)r * Iin + src_col;
            float4 f0 = *(const float4*)s;
            float4 f1 = *(const float4*)(s + 4);
            st = pack8(f0, f1);
        } else if (r < src_rows && src_col < Iin) {
            const float* s = src + (size_t)r * Iin + src_col;
            #pragma unroll
            for (int e = 0; e < 8; ++e) {
                float v = (src_col + e < Iin) ? s[e] : 0.f;
                st[e] = f2bf(v);
            }
        } else {
            #pragma unroll
            for (int e = 0; e < 8; ++e) st[e] = 0;
        }
        *(short8*)&dst[(size_t)r * Kp + (size_t)s_dst * 8] = st;
    }
}

// ---------------------------------------------------------------------------
// Kernel 3: 256x256 GEMM z = x @ w_int^T (bf16 MFMA) + interaction epilogue.
// 8 waves (2M x 4N), wave-tile 128x64 (M_rep=8, N_rep=4). BK=32.
// A-fragments: GLOBAL -> REGISTER (no LDS), double-set, prefetched 1 section
// ahead under counted vmcnt(10). A-strip is L2-resident per XCD (tm = blk&7).
// B: global_load_lds into a 4-slot ring, staged 2 sections ahead.
// One barrier per section; vmcnt never drains to 0 until the tail.
// ---------------------------------------------------------------------------
__global__ __launch_bounds__(512) void gemm_ag(
    const short* __restrict__ xb, const short* __restrict__ wb,
    const float* __restrict__ xf, const float* __restrict__ finw,
    float* __restrict__ out) {

    __shared__ short lsB[4][8192];   // [slot][256 rows x 32 cols]
    __shared__ float part[256][3];

    const int tid  = threadIdx.x;
    const int lane = tid & 63;
    const int wid  = tid >> 6;       // 0..7
    const int wr   = wid >> 2;       // 0..1  (M half)
    const int wc   = wid & 3;        // 0..3  (N quarter)
    const int l15  = lane & 15;
    const int koff = (((lane >> 4) ^ ((lane >> 1) & 3)) << 3);  // swizzled k-slot

    // XCD-locality mapping: round-robin dispatch puts blk%8 on XCD blk%8;
    // tm = blk&7 makes every block on an XCD share ONE 3.2 MB A-strip (L2-fit).
    int tm = (int)blockIdx.x & 7;
    int tn = (int)blockIdx.x >> 3;   // 0..24
    int bm0 = tm << 8;
    int in0 = tn << 8;

    const int srow = lane >> 2;      // staging: row within 16-row wave chunk
    const int ssl  = lane & 3;       // staging: 16B slot within row
    const short* zptr = wb + 6176;   // 16 B of guaranteed zeros (row 0, cols>=Iin)

    f32x4 acc[8][4];
    #pragma unroll
    for (int m = 0; m < 8; ++m)
        #pragma unroll
        for (int n = 0; n < 4; ++n)
            acc[m][n] = (f32x4){0.f, 0.f, 0.f, 0.f};

    auto stageB = [&](int tk, int h) {
        int row = h * 128 + wid * 16 + srow;
        int rg  = in0 + row;
        const short* src = (rg < NpW)
            ? wb + (size_t)rg * Kp + tk * 32 + ssl * 8 : zptr;
        stage_chunk(src, &lsB[tk & 3][(h * 128 + wid * 16) * 32]);
    };
    auto ldB = [&](int slot, int n) -> short8 {
        return *(const short8*)&lsB[slot][(wc * 64 + n * 16 + l15) * 32 + koff];
    };

    // per-lane A base: row = bm0 + wr*128 + m*16 + l15, col = kt*32 + koff
    const short* aBase = xb + (size_t)(bm0 + wr * 128 + l15) * Kp + koff;

    short8 afA[8], afB[8], bf[4];

    // prologue: B tiles 0,1 staged (4 vm); A frags for tile 0 (8 vm) -> 12 out
    stageB(0, 0); stageB(0, 1);
    stageB(1, 0); stageB(1, 1);
    #pragma unroll
    for (int m = 0; m < 8; ++m)
        afA[m] = *(const short8*)(aBase + (size_t)m * 16 * Kp);

// Section KT: [top wait TW] barrier | bf(KT) ds_reads | issue af(KT+1)->NXT |
//             issue stageB(KT+2) | [PW + lgkm(0)] | 32 MFMA on CUR.
// Steady state: outstanding at top = af(KT)8 + B(KT+1)2 = 10 (TW vacuous);
// pre-MFMA: outstanding 20, vmcnt(10) drains af(KT) + B(KT+1).
#define SEC(KT, CUR, NXT, TW, PW, DO_AF, DO_STB)                          \
    {                                                                     \
        asm volatile("s_waitcnt " TW ::: "memory");                       \
        __builtin_amdgcn_s_barrier();                                     \
        const int _sl = (KT) & 3;                                         \
        _Pragma("unroll")                                                 \
        for (int n = 0; n < 4; ++n) bf[n] = ldB(_sl, n);                  \
        __builtin_amdgcn_sched_barrier(0);                                \
        if (DO_AF) {                                                      \
            const short* _ap = aBase + (size_t)((KT) + 1) * 32;           \
            _Pragma("unroll")                                             \
            for (int m = 0; m < 8; ++m)                                   \
                NXT[m] = *(const short8*)(_ap + (size_t)m * 16 * Kp);     \
        }                                                                 \
        __builtin_amdgcn_sched_barrier(0);                                \
        if (DO_STB) { stageB((KT) + 2, 0); stageB((KT) + 2, 1); }         \
        __builtin_amdgcn_sched_barrier(0);                                \
        asm volatile("s_waitcnt " PW " lgkmcnt(0)" ::: "memory");         \
        __builtin_amdgcn_sched_barrier(0);                                \
        __builtin_amdgcn_s_setprio(1);                                    \
        _Pragma("unroll")                                                 \
        for (int m = 0; m < 8; ++m)                                       \
            _Pragma("unroll")                                             \
            for (int n = 0; n < 4; ++n)                                   \
                acc[m][n] = __builtin_amdgcn_mfma_f32_16x16x32_bf16(      \
                    CUR[m], bf[n], acc[m][n], 0, 0, 0);                   \
        __builtin_amdgcn_s_setprio(0);                                    \
        __builtin_amdgcn_sched_barrier(0);                                \
    }

    for (int i = 0; i < 96; ++i) {          // kt = 0..191
        int kt = 2 * i;
        SEC(kt,     afA, afB, "vmcnt(10)", "vmcnt(10)", true, true);
        SEC(kt + 1, afB, afA, "vmcnt(10)", "vmcnt(10)", true, true);
    }
    // kt=192: issues af(193), no more B staging; drain af(192)+B(193) -> vmcnt(8)
    SEC(192, afA, afB, "vmcnt(10)", "vmcnt(8)", true,  false);
    // kt=193: nothing issued; drain af(193)
    SEC(193, afB, afA, "vmcnt(8)",  "vmcnt(0)", false, false);
#undef SEC

    // ---- epilogue: out[b,o] += sum_gi finw[o,3+gi] * x[b,gi] * z[b,gi]
    __syncthreads();
    for (int t = tid; t < 768; t += 512) ((float*)part)[t] = 0.f;
    __syncthreads();

    int q4 = lane >> 4;
    #pragma unroll
    for (int m = 0; m < 8; ++m) {
        #pragma unroll
        for (int r = 0; r < 4; ++r) {
            int lr = wr * 128 + m * 16 + q4 * 4 + r;   // 0..255
            int bg = bm0 + lr;
            float s0 = 0.f, s1 = 0.f, s2 = 0.f;
            #pragma unroll
            for (int n = 0; n < 4; ++n) {
                int gi = in0 + wc * 64 + n * 16 + l15;
                if (gi < Iin) {
                    float inter = acc[m][n][r] * xf[(size_t)bg * Iin + gi];
                    s0 += inter * finw[(size_t)0 * IF + 3 + gi];
                    s1 += inter * finw[(size_t)1 * IF + 3 + gi];
                    s2 += inter * finw[(size_t)2 * IF + 3 + gi];
                }
            }
            #pragma unroll
            for (int off = 1; off < 16; off <<= 1) {
                s0 += __shfl_xor(s0, off, 64);
                s1 += __shfl_xor(s1, off, 64);
                s2 += __shfl_xor(s2, off, 64);
            }
            if (l15 == 0) {
                atomicAdd(&part[lr][0], s0);
                atomicAdd(&part[lr][1], s1);
                atomicAdd(&part[lr][2], s2);
            }
        }
    }
    __syncthreads();
    for (int t = tid; t < 768; t += 512) {
        int lr = t / 3, o = t - lr * 3;
        atomicAdd(&out[(size_t)(bm0 + lr) * 3 + o], part[lr][o]);
    }
}

// ---------------------------------------------------------------------------
// Fallback (no workspace): self-staged 2-barrier kernel (mask-7 swizzle).
// ---------------------------------------------------------------------------
__global__ __launch_bounds__(256) void gemm_fallback(
    const float* __restrict__ xf, const float* __restrict__ wf,
    const float* __restrict__ finw, float* __restrict__ out) {

    __shared__ short lsA[128 * 64];
    __shared__ short lsB[128 * 64];
    __shared__ float part[128][3];

    int tid  = threadIdx.x;
    int lane = tid & 63;
    int wid  = tid >> 6;
    int wm   = wid & 1;
    int wn   = wid >> 1;

    int ntiles = (Bsz / 128) * (NpW / 128);
    int tile = (blockIdx.x & 7) * (ntiles >> 3) + (blockIdx.x >> 3);
    int tm = tile & 15;
    int tn = tile >> 4;
    int bm0 = tm << 7;
    int in0 = tn << 7;

    f32x4 acc[4][4];
    #pragma unroll
    for (int m = 0; m < 4; ++m)
        #pragma unroll
        for (int n = 0; n < 4; ++n)
            acc[m][n] = (f32x4){0.f, 0.f, 0.f, 0.f};

    for (int k0 = 0; k0 < Kp; k0 += 64) {
        #pragma unroll
        for (int it = 0; it < 4; ++it) {
            int idx = it * 256 + tid;
            int r   = idx >> 3;
            int seg = idx & 7;
            int kc  = k0 + seg * 8;
            int sd  = (seg ^ (r & 7)) << 3;
            {
                const float* s = xf + (size_t)(bm0 + r) * Iin + kc;
                short8 st;
                if (kc + 8 <= Iin) {
                    float4 f0 = *(const float4*)s;
                    float4 f1 = *(const float4*)(s + 4);
                    st = pack8(f0, f1);
                } else {
                    #pragma unroll
                    for (int e = 0; e < 8; ++e) {
                        float v = (kc + e < Iin) ? s[e] : 0.f;
                        st[e] = f2bf(v);
                    }
                }
                *(short8*)&lsA[r * 64 + sd] = st;
            }
            {
                int grow = in0 + r;
                short8 st;
                if (grow < Iin && kc + 8 <= Iin) {
                    const float* s = wf + (size_t)grow * Iin + kc;
                    float4 f0 = *(const float4*)s;
                    float4 f1 = *(const float4*)(s + 4);
                    st = pack8(f0, f1);
                } else if (grow < Iin) {
                    const float* s = wf + (size_t)grow * Iin + kc;
                    #pragma unroll
                    for (int e = 0; e < 8; ++e) {
                        float v = (kc + e < Iin) ? s[e] : 0.f;
                        st[e] = f2bf(v);
                    }
                } else {
                    #pragma unroll
                    for (int e = 0; e < 8; ++e) st[e] = 0;
                }
                *(short8*)&lsB[r * 64 + sd] = st;
            }
        }
        __syncthreads();

        #pragma unroll
        for (int kk = 0; kk < 2; ++kk) {
            int q = (kk << 2) + (lane >> 4);
            short8 af[4], bfr[4];
            #pragma unroll
            for (int m = 0; m < 4; ++m) {
                int R = wm * 64 + m * 16 + (lane & 15);
                af[m] = *(const short8*)&lsA[R * 64 + ((q ^ (R & 7)) << 3)];
            }
            #pragma unroll
            for (int n = 0; n < 4; ++n) {
                int R = wn * 64 + n * 16 + (lane & 15);
                bfr[n] = *(const short8*)&lsB[R * 64 + ((q ^ (R & 7)) << 3)];
            }
            #pragma unroll
            for (int m = 0; m < 4; ++m)
                #pragma unroll
                for (int n = 0; n < 4; ++n)
                    acc[m][n] = __builtin_amdgcn_mfma_f32_16x16x32_bf16(
                        af[m], bfr[n], acc[m][n], 0, 0, 0);
        }
        __syncthreads();
    }

    for (int t = tid; t < 384; t += 256) ((float*)part)[t] = 0.f;
    __syncthreads();

    #pragma unroll
    for (int m = 0; m < 4; ++m) {
        int rowbase = bm0 + wm * 64 + m * 16 + ((lane >> 4) << 2);
        #pragma unroll
        for (int r = 0; r < 4; ++r) {
            int b = rowbase + r;
            float s0 = 0.f, s1 = 0.f, s2 = 0.f;
            #pragma unroll
            for (int n = 0; n < 4; ++n) {
                int gi = in0 + wn * 64 + n * 16 + (lane & 15);
                if (gi < Iin) {
                    float inter = acc[m][n][r] * xf[(size_t)b * Iin + gi];
                    s0 += inter * finw[(size_t)0 * IF + 3 + gi];
                    s1 += inter * finw[(size_t)1 * IF + 3 + gi];
                    s2 += inter * finw[(size_t)2 * IF + 3 + gi];
                }
            }
            #pragma unroll
            for (int off = 1; off < 16; off <<= 1) {
                s0 += __shfl_xor(s0, off, 64);
                s1 += __shfl_xor(s1, off, 64);
                s2 += __shfl_xor(s2, off, 64);
            }
            if ((lane & 15) == 0) {
                int lr = b - bm0;
                atomicAdd(&part[lr][0], s0);
                atomicAdd(&part[lr][1], s1);
                atomicAdd(&part[lr][2], s2);
            }
        }
    }
    __syncthreads();
    for (int t = tid; t < 384; t += 256) {
        int lr = t / 3, o = t - lr * 3;
        atomicAdd(&out[(size_t)(bm0 + lr) * 3 + o], part[lr][o]);
    }
}

// ---------------------------------------------------------------------------
extern "C" void kernel_launch(void* const* d_in, const int* in_sizes, int n_in,
                              void* d_out, int out_size, void* d_ws, size_t ws_size,
                              hipStream_t stream) {
    const float* x     = (const float*)d_in[0];
    const float* lin_w = (const float*)d_in[1];
    const float* lin_b = (const float*)d_in[2];
    const float* w_int = (const float*)d_in[3];
    const float* fin_w = (const float*)d_in[4];
    const float* fin_b = (const float*)d_in[5];
    float* out = (float*)d_out;

    linear_init_kernel<<<Bsz / 4, 256, 0, stream>>>(x, lin_w, lin_b, fin_w, fin_b, out);

    const size_t xb_elems = (size_t)Bsz * Kp;    // 12,713,984
    const size_t wb_elems = (size_t)NpW * Kp;    // 38,936,576
    const size_t need = (xb_elems + wb_elems) * sizeof(short);   // 103.3 MB

    if (ws_size >= need) {
        short* xb = (short*)d_ws;
        short* wb = xb + xb_elems;
        convert_kernel<<<2048, 256, 0, stream>>>(x, xb, Bsz, Bsz);
        convert_kernel<<<2048, 256, 0, stream>>>(w_int, wb, NpW, Iin);
        gemm_ag<<<MT * NTN, 512, 0, stream>>>(xb, wb, x, fin_w, out);
    } else {
        const int ntiles = (Bsz / 128) * (NpW / 128);
        gemm_fallback<<<ntiles, 256, 0, stream>>>(x, w_int, fin_w, out);
    }
}

// Round 8
// 285.613 us; speedup vs baseline: 1.4195x; 1.4195x over previous
//
#include <hip/hip_runtime.h>
#include <hip/hip_bf16.h>

// Problem constants
constexpr int Bsz = 2048;   // batch
constexpr int Iin = 6156;   // input features (= K = N of the big GEMM)
constexpr int IF  = 6159;   // I + O (fin_w row length)
constexpr int Kp  = 6208;   // K padded to multiple of 64 (97 * 64)
constexpr int NpW = 6272;   // w rows stored in ws (multiple of 128)
constexpr int NSTEP = Kp / 64;           // 97 K-steps (BK=64)
constexpr int MT  = Bsz / 256;           // 8 M-tiles
constexpr int NTN = 25;                  // N-tiles of 256 (cols 6272..6399 virtual zeros)

typedef __attribute__((ext_vector_type(8))) short short8;
typedef __attribute__((ext_vector_type(4))) float f32x4;

#define AS1 __attribute__((address_space(1)))
#define AS3 __attribute__((address_space(3)))

__device__ __forceinline__ short f2bf(float f) {
    union { float f; unsigned u; } v; v.f = f;
    unsigned r = v.u + 0x7FFFu + ((v.u >> 16) & 1u);   // RNE
    return (short)(r >> 16);
}

__device__ __forceinline__ short8 pack8(float4 a, float4 b) {
    short8 r;
    r[0] = f2bf(a.x); r[1] = f2bf(a.y); r[2] = f2bf(a.z); r[3] = f2bf(a.w);
    r[4] = f2bf(b.x); r[5] = f2bf(b.y); r[6] = f2bf(b.z); r[7] = f2bf(b.w);
    return r;
}

__device__ __forceinline__ void stage_chunk(const short* src, const short* ldsbase) {
    __builtin_amdgcn_global_load_lds((const AS1 void*)src, (AS3 void*)ldsbase, 16, 0, 0);
}

// ---------------------------------------------------------------------------
// Kernel 1: linear path + bias; fully initializes d_out.
// ---------------------------------------------------------------------------
__global__ void linear_init_kernel(const float* __restrict__ x,
                                   const float* __restrict__ lin_w,
                                   const float* __restrict__ lin_b,
                                   const float* __restrict__ fin_w,
                                   const float* __restrict__ fin_b,
                                   float* __restrict__ out) {
    int wid  = threadIdx.x >> 6;
    int lane = threadIdx.x & 63;
    int b = blockIdx.x * 4 + wid;
    if (b >= Bsz) return;
    const float4* xr = (const float4*)(x + (size_t)b * Iin);
    const float4* w0 = (const float4*)(lin_w);
    const float4* w1 = (const float4*)(lin_w + Iin);
    const float4* w2 = (const float4*)(lin_w + 2 * Iin);
    float s0 = 0.f, s1 = 0.f, s2 = 0.f;
    for (int i = lane; i < Iin / 4; i += 64) {
        float4 xv = xr[i];
        float4 a0 = w0[i], a1 = w1[i], a2 = w2[i];
        s0 += xv.x * a0.x + xv.y * a0.y + xv.z * a0.z + xv.w * a0.w;
        s1 += xv.x * a1.x + xv.y * a1.y + xv.z * a1.z + xv.w * a1.w;
        s2 += xv.x * a2.x + xv.y * a2.y + xv.z * a2.z + xv.w * a2.w;
    }
    #pragma unroll
    for (int off = 1; off < 64; off <<= 1) {
        s0 += __shfl_xor(s0, off, 64);
        s1 += __shfl_xor(s1, off, 64);
        s2 += __shfl_xor(s2, off, 64);
    }
    if (lane == 0) {
        float l0 = s0 + lin_b[0], l1 = s1 + lin_b[1], l2 = s2 + lin_b[2];
        #pragma unroll
        for (int o = 0; o < 3; ++o) {
            out[b * 3 + o] = fin_b[o]
                + fin_w[(size_t)o * IF + 0] * l0
                + fin_w[(size_t)o * IF + 1] * l1
                + fin_w[(size_t)o * IF + 2] * l2;
        }
    }
}

// ---------------------------------------------------------------------------
// Kernel 2: f32 -> bf16 conversion, zero padding, + 8-slot XOR swizzle for
// BK=64 rows: within each 8-slot (64-col) block, ws slot sub holds source
// segment sub ^ (r&7).  Read at slot q^(r&7) -> conflict-spread fragments.
// ---------------------------------------------------------------------------
__global__ void convert_kernel(const float* __restrict__ src,
                               short* __restrict__ dst,
                               int rows, int src_rows) {
    const int segs = Kp / 8;   // 776
    int total = rows * segs;
    for (int c = blockIdx.x * blockDim.x + threadIdx.x; c < total;
         c += gridDim.x * blockDim.x) {
        int r     = c / segs;
        int s_dst = c - r * segs;
        int blk   = s_dst >> 3;
        int sub   = s_dst & 7;
        int src_col = (blk << 6) + ((sub ^ (r & 7)) << 3);
        short8 st;
        if (r < src_rows && src_col + 8 <= Iin) {
            const float* s = src + (size_t)r * Iin + src_col;
            float4 f0 = *(const float4*)s;
            float4 f1 = *(const float4*)(s + 4);
            st = pack8(f0, f1);
        } else if (r < src_rows && src_col < Iin) {
            const float* s = src + (size_t)r * Iin + src_col;
            #pragma unroll
            for (int e = 0; e < 8; ++e) {
                float v = (src_col + e < Iin) ? s[e] : 0.f;
                st[e] = f2bf(v);
            }
        } else {
            #pragma unroll
            for (int e = 0; e < 8; ++e) st[e] = 0;
        }
        *(short8*)&dst[(size_t)r * Kp + (size_t)s_dst * 8] = st;
    }
}

// ---------------------------------------------------------------------------
// Kernel 3: 256x256 GEMM z = x @ w_int^T (bf16 MFMA) + interaction epilogue.
// m201-style: BK=64, 2 LDS buffers, 4 phases/K-step, each phase:
//   { ds_reads(cur) ; stage 1 half-tile(next) ; counted vmcnt ; barrier ;
//     lgkmcnt(0)+sched_barrier ; setprio(1) 16 MFMA setprio(0) ; barrier }
// Interleaved m/n mapping gives half-locality: phase needs exactly one new
// half (A0,B0,B1,A1 order), waits vmcnt(4) at P1,P2,P4 (none at P3).
// 8 waves 2M x 4N; per-wave reads/phase = {12,4,8,0} with register reuse.
// ---------------------------------------------------------------------------
__global__ __launch_bounds__(512, 2) void gemm_m201(
    const short* __restrict__ xb, const short* __restrict__ wb,
    const float* __restrict__ xf, const float* __restrict__ finw,
    float* __restrict__ out) {

    __shared__ short lsA[2][256 * 64];   // [buf][256 rows x 64 cols]
    __shared__ short lsB[2][256 * 64];
    __shared__ float part[256][3];

    const int tid  = threadIdx.x;
    const int lane = tid & 63;
    const int wid  = tid >> 6;       // 0..7
    const int wr   = wid >> 2;       // 0..1  (M half)
    const int wc   = wid & 3;        // 0..3  (N quarter)
    const int l15  = lane & 15;
    const int qhi  = lane >> 4;      // 0..3 (k sub-segment within 32-k)

    // bijective XCD swizzle: 200 blocks = 8 XCDs x 25
    int swz = ((int)blockIdx.x & 7) * NTN + ((int)blockIdx.x >> 3);
    int tm = swz & 7;
    int tn = swz >> 3;
    int bm0 = tm << 8;
    int in0 = tn << 8;

    const short* zptr = wb + 6176;   // 16 B of guaranteed zeros (row 0)

    f32x4 acc[8][4];
    #pragma unroll
    for (int m = 0; m < 8; ++m)
        #pragma unroll
        for (int n = 0; n < 4; ++n)
            acc[m][n] = (f32x4){0.f, 0.f, 0.f, 0.f};

    // ---- staging: half h (rows h*128..+127), chunk j (0,1); 2 loads/half/thread
    auto stageA = [&](int t, int h, int j) {
        int sidx = j * 512 + tid;                 // thread-slot (8 per 128B row)
        int row  = sidx >> 3, seg = sidx & 7;
        const short* src = xb + (size_t)(bm0 + h * 128 + row) * Kp + t * 64 + seg * 8;
        stage_chunk(src, &lsA[t & 1][h * 8192 + (j * 512 + wid * 64) * 8]);
    };
    auto stageB = [&](int t, int h, int j) {
        int sidx = j * 512 + tid;
        int row  = sidx >> 3, seg = sidx & 7;
        int rg   = in0 + h * 128 + row;
        const short* src = (rg < NpW)
            ? wb + (size_t)rg * Kp + t * 64 + seg * 8 : zptr;
        stage_chunk(src, &lsB[t & 1][h * 8192 + (j * 512 + wid * 64) * 8]);
    };

    // ---- fragment reads (interleaved row mapping; swizzled k-slot)
    auto ldA = [&](const short* la, int m, int kk) -> short8 {
        int row = (m < 4 ? wr * 64 + m * 16 : 128 + wr * 64 + (m - 4) * 16) + l15;
        int q = kk * 4 + qhi;
        return *(const short8*)&la[row * 64 + ((q ^ (row & 7)) << 3)];
    };
    auto ldB = [&](const short* lb, int n, int kk) -> short8 {
        int row = (n < 2 ? wc * 32 + n * 16 : 128 + wc * 32 + (n - 2) * 16) + l15;
        int q = kk * 4 + qhi;
        return *(const short8*)&lb[row * 64 + ((q ^ (row & 7)) << 3)];
    };

    short8 af[4][2];    // current m-quad, both kk
    short8 bfr[4][2];   // all n, both kk (live across the whole step)

    // prologue: stage step 0 halves in order A0,B0,B1,A1 (8 loads/thread)
    stageA(0, 0, 0); stageA(0, 0, 1);
    stageB(0, 0, 0); stageB(0, 0, 1);
    stageB(0, 1, 0); stageB(0, 1, 1);
    stageA(0, 1, 0); stageA(0, 1, 1);
    asm volatile("s_waitcnt vmcnt(4)" ::: "memory");   // A0(0),B0(0) landed
    __builtin_amdgcn_s_barrier();

#define MFMA_Q(MB, NB)                                                        \
    __builtin_amdgcn_s_setprio(1);                                            \
    _Pragma("unroll")                                                         \
    for (int mi = 0; mi < 4; ++mi)                                            \
        _Pragma("unroll")                                                     \
        for (int ni = 0; ni < 2; ++ni)                                        \
            _Pragma("unroll")                                                 \
            for (int kk = 0; kk < 2; ++kk)                                    \
                acc[(MB)*4 + mi][(NB)*2 + ni] =                               \
                    __builtin_amdgcn_mfma_f32_16x16x32_bf16(                  \
                        af[mi][kk], bfr[(NB)*2 + ni][kk],                     \
                        acc[(MB)*4 + mi][(NB)*2 + ni], 0, 0, 0);              \
    __builtin_amdgcn_s_setprio(0);

#define PH_TAIL(WAITSTR)                                                      \
    __builtin_amdgcn_sched_barrier(0);                                        \
    asm volatile(WAITSTR ::: "memory");                                       \
    __builtin_amdgcn_s_barrier();                                             \
    asm volatile("s_waitcnt lgkmcnt(0)" ::: "memory");                        \
    __builtin_amdgcn_sched_barrier(0);

#define PH_END                                                                \
    __builtin_amdgcn_sched_barrier(0);                                        \
    __builtin_amdgcn_s_barrier();

// One K-step: phases P1..P4. DO_ST: stage step t+1. Tail waits differ.
#define STEP(T, DO_ST, W1, W2, W4)                                            \
    {                                                                         \
        const short* la = lsA[(T) & 1];                                       \
        const short* lb = lsB[(T) & 1];                                       \
        /* P1: reads A-quad0 + B nq0 ; stage A0(t+1) ; MFMA q(0,0) */         \
        _Pragma("unroll")                                                     \
        for (int mi = 0; mi < 4; ++mi) {                                      \
            af[mi][0] = ldA(la, mi, 0); af[mi][1] = ldA(la, mi, 1);           \
        }                                                                     \
        _Pragma("unroll")                                                     \
        for (int ni = 0; ni < 2; ++ni) {                                      \
            bfr[ni][0] = ldB(lb, ni, 0); bfr[ni][1] = ldB(lb, ni, 1);         \
        }                                                                     \
        __builtin_amdgcn_sched_barrier(0);                                    \
        if (DO_ST) { stageA((T) + 1, 0, 0); stageA((T) + 1, 0, 1); }          \
        PH_TAIL(W1)                                                           \
        MFMA_Q(0, 0)                                                          \
        PH_END                                                                \
        /* P2: reads B nq1 ; stage B0(t+1) ; MFMA q(0,1) */                   \
        _Pragma("unroll")                                                     \
        for (int ni = 0; ni < 2; ++ni) {                                      \
            bfr[2 + ni][0] = ldB(lb, 2 + ni, 0);                              \
            bfr[2 + ni][1] = ldB(lb, 2 + ni, 1);                              \
        }                                                                     \
        __builtin_amdgcn_sched_barrier(0);                                    \
        if (DO_ST) { stageB((T) + 1, 0, 0); stageB((T) + 1, 0, 1); }          \
        PH_TAIL(W2)                                                           \
        MFMA_Q(0, 1)                                                          \
        PH_END                                                                \
        /* P3: reads A-quad1 ; stage B1(t+1) ; MFMA q(1,0) ; no wait */       \
        _Pragma("unroll")                                                     \
        for (int mi = 0; mi < 4; ++mi) {                                      \
            af[mi][0] = ldA(la, 4 + mi, 0); af[mi][1] = ldA(la, 4 + mi, 1);   \
        }                                                                     \
        __builtin_amdgcn_sched_barrier(0);                                    \
        if (DO_ST) { stageB((T) + 1, 1, 0); stageB((T) + 1, 1, 1); }          \
        __builtin_amdgcn_sched_barrier(0);                                    \
        __builtin_amdgcn_s_barrier();                                         \
        asm volatile("s_waitcnt lgkmcnt(0)" ::: "memory");                    \
        __builtin_amdgcn_sched_barrier(0);                                    \
        MFMA_Q(1, 0)                                                          \
        PH_END                                                                \
        /* P4: no reads ; stage A1(t+1) ; MFMA q(1,1) */                      \
        if (DO_ST) { stageA((T) + 1, 1, 0); stageA((T) + 1, 1, 1); }          \
        PH_TAIL(W4)                                                           \
        MFMA_Q(1, 1)                                                          \
        PH_END                                                                \
    }

    for (int t = 0; t < NSTEP - 1; ++t) {
        STEP(t, true, "s_waitcnt vmcnt(4)", "s_waitcnt vmcnt(4)",
                      "s_waitcnt vmcnt(4)");
    }
    STEP(NSTEP - 1, false, "s_waitcnt vmcnt(2)", "s_waitcnt vmcnt(0)",
                           "s_nop 0");
#undef STEP
#undef PH_TAIL
#undef PH_END
#undef MFMA_Q

    // ---- epilogue: out[b,o] += sum_gi finw[o,3+gi] * x[b,gi] * z[b,gi]
    __syncthreads();
    for (int t = tid; t < 768; t += 512) ((float*)part)[t] = 0.f;
    __syncthreads();

    #pragma unroll
    for (int m = 0; m < 8; ++m) {
        int mrow = (m < 4 ? wr * 64 + m * 16 : 128 + wr * 64 + (m - 4) * 16);
        #pragma unroll
        for (int r = 0; r < 4; ++r) {
            int lr = mrow + qhi * 4 + r;          // 0..255
            int bg = bm0 + lr;
            float s0 = 0.f, s1 = 0.f, s2 = 0.f;
            #pragma unroll
            for (int n = 0; n < 4; ++n) {
                int ncol = (n < 2 ? wc * 32 + n * 16 : 128 + wc * 32 + (n - 2) * 16);
                int gi = in0 + ncol + l15;
                if (gi < Iin) {
                    float inter = acc[m][n][r] * xf[(size_t)bg * Iin + gi];
                    s0 += inter * finw[(size_t)0 * IF + 3 + gi];
                    s1 += inter * finw[(size_t)1 * IF + 3 + gi];
                    s2 += inter * finw[(size_t)2 * IF + 3 + gi];
                }
            }
            #pragma unroll
            for (int off = 1; off < 16; off <<= 1) {
                s0 += __shfl_xor(s0, off, 64);
                s1 += __shfl_xor(s1, off, 64);
                s2 += __shfl_xor(s2, off, 64);
            }
            if (l15 == 0) {
                atomicAdd(&part[lr][0], s0);
                atomicAdd(&part[lr][1], s1);
                atomicAdd(&part[lr][2], s2);
            }
        }
    }
    __syncthreads();
    for (int t = tid; t < 768; t += 512) {
        int lr = t / 3, o = t - lr * 3;
        atomicAdd(&out[(size_t)(bm0 + lr) * 3 + o], part[lr][o]);
    }
}

// ---------------------------------------------------------------------------
// Fallback (no workspace): self-staged 2-barrier kernel (mask-7 swizzle).
// ---------------------------------------------------------------------------
__global__ __launch_bounds__(256) void gemm_fallback(
    const float* __restrict__ xf, const float* __restrict__ wf,
    const float* __restrict__ finw, float* __restrict__ out) {

    __shared__ short lsA[128 * 64];
    __shared__ short lsB[128 * 64];
    __shared__ float part[128][3];

    int tid  = threadIdx.x;
    int lane = tid & 63;
    int wid  = tid >> 6;
    int wm   = wid & 1;
    int wn   = wid >> 1;

    int ntiles = (Bsz / 128) * (NpW / 128);
    int tile = (blockIdx.x & 7) * (ntiles >> 3) + (blockIdx.x >> 3);
    int tm = tile & 15;
    int tn = tile >> 4;
    int bm0 = tm << 7;
    int in0 = tn << 7;

    f32x4 acc[4][4];
    #pragma unroll
    for (int m = 0; m < 4; ++m)
        #pragma unroll
        for (int n = 0; n < 4; ++n)
            acc[m][n] = (f32x4){0.f, 0.f, 0.f, 0.f};

    for (int k0 = 0; k0 < Kp; k0 += 64) {
        #pragma unroll
        for (int it = 0; it < 4; ++it) {
            int idx = it * 256 + tid;
            int r   = idx >> 3;
            int seg = idx & 7;
            int kc  = k0 + seg * 8;
            int sd  = (seg ^ (r & 7)) << 3;
            {
                const float* s = xf + (size_t)(bm0 + r) * Iin + kc;
                short8 st;
                if (kc + 8 <= Iin) {
                    float4 f0 = *(const float4*)s;
                    float4 f1 = *(const float4*)(s + 4);
                    st = pack8(f0, f1);
                } else {
                    #pragma unroll
                    for (int e = 0; e < 8; ++e) {
                        float v = (kc + e < Iin) ? s[e] : 0.f;
                        st[e] = f2bf(v);
                    }
                }
                *(short8*)&lsA[r * 64 + sd] = st;
            }
            {
                int grow = in0 + r;
                short8 st;
                if (grow < Iin && kc + 8 <= Iin) {
                    const float* s = wf + (size_t)grow * Iin + kc;
                    float4 f0 = *(const float4*)s;
                    float4 f1 = *(const float4*)(s + 4);
                    st = pack8(f0, f1);
                } else if (grow < Iin) {
                    const float* s = wf + (size_t)grow * Iin + kc;
                    #pragma unroll
                    for (int e = 0; e < 8; ++e) {
                        float v = (kc + e < Iin) ? s[e] : 0.f;
                        st[e] = f2bf(v);
                    }
                } else {
                    #pragma unroll
                    for (int e = 0; e < 8; ++e) st[e] = 0;
                }
                *(short8*)&lsB[r * 64 + sd] = st;
            }
        }
        __syncthreads();

        #pragma unroll
        for (int kk = 0; kk < 2; ++kk) {
            int q = (kk << 2) + (lane >> 4);
            short8 af[4], bfr[4];
            #pragma unroll
            for (int m = 0; m < 4; ++m) {
                int R = wm * 64 + m * 16 + (lane & 15);
                af[m] = *(const short8*)&lsA[R * 64 + ((q ^ (R & 7)) << 3)];
            }
            #pragma unroll
            for (int n = 0; n < 4; ++n) {
                int R = wn * 64 + n * 16 + (lane & 15);
                bfr[n] = *(const short8*)&lsB[R * 64 + ((q ^ (R & 7)) << 3)];
            }
            #pragma unroll
            for (int m = 0; m < 4; ++m)
                #pragma unroll
                for (int n = 0; n < 4; ++n)
                    acc[m][n] = __builtin_amdgcn_mfma_f32_16x16x32_bf16(
                        af[m], bfr[n], acc[m][n], 0, 0, 0);
        }
        __syncthreads();
    }

    for (int t = tid; t < 384; t += 256) ((float*)part)[t] = 0.f;
    __syncthreads();

    #pragma unroll
    for (int m = 0; m < 4; ++m) {
        int rowbase = bm0 + wm * 64 + m * 16 + ((lane >> 4) << 2);
        #pragma unroll
        for (int r = 0; r < 4; ++r) {
            int b = rowbase + r;
            float s0 = 0.f, s1 = 0.f, s2 = 0.f;
            #pragma unroll
            for (int n = 0; n < 4; ++n) {
                int gi = in0 + wn * 64 + n * 16 + (lane & 15);
                if (gi < Iin) {
                    float inter = acc[m][n][r] * xf[(size_t)b * Iin + gi];
                    s0 += inter * finw[(size_t)0 * IF + 3 + gi];
                    s1 += inter * finw[(size_t)1 * IF + 3 + gi];
                    s2 += inter * finw[(size_t)2 * IF + 3 + gi];
                }
            }
            #pragma unroll
            for (int off = 1; off < 16; off <<= 1) {
                s0 += __shfl_xor(s0, off, 64);
                s1 += __shfl_xor(s1, off, 64);
                s2 += __shfl_xor(s2, off, 64);
            }
            if ((lane & 15) == 0) {
                int lr = b - bm0;
                atomicAdd(&part[lr][0], s0);
                atomicAdd(&part[lr][1], s1);
                atomicAdd(&part[lr][2], s2);
            }
        }
    }
    __syncthreads();
    for (int t = tid; t < 384; t += 256) {
        int lr = t / 3, o = t - lr * 3;
        atomicAdd(&out[(size_t)(bm0 + lr) * 3 + o], part[lr][o]);
    }
}

// ---------------------------------------------------------------------------
extern "C" void kernel_launch(void* const* d_in, const int* in_sizes, int n_in,
                              void* d_out, int out_size, void* d_ws, size_t ws_size,
                              hipStream_t stream) {
    const float* x     = (const float*)d_in[0];
    const float* lin_w = (const float*)d_in[1];
    const float* lin_b = (const float*)d_in[2];
    const float* w_int = (const float*)d_in[3];
    const float* fin_w = (const float*)d_in[4];
    const float* fin_b = (const float*)d_in[5];
    float* out = (float*)d_out;

    linear_init_kernel<<<Bsz / 4, 256, 0, stream>>>(x, lin_w, lin_b, fin_w, fin_b, out);

    const size_t xb_elems = (size_t)Bsz * Kp;    // 12,713,984
    const size_t wb_elems = (size_t)NpW * Kp;    // 38,936,576
    const size_t need = (xb_elems + wb_elems) * sizeof(short);   // 103.3 MB

    if (ws_size >= need) {
        short* xb = (short*)d_ws;
        short* wb = xb + xb_elems;
        convert_kernel<<<2048, 256, 0, stream>>>(x, xb, Bsz, Bsz);
        convert_kernel<<<2048, 256, 0, stream>>>(w_int, wb, NpW, Iin);
        gemm_m201<<<MT * NTN, 512, 0, stream>>>(xb, wb, x, fin_w, out);
    } else {
        const int ntiles = (Bsz / 128) * (NpW / 128);
        gemm_fallback<<<ntiles, 256, 0, stream>>>(x, w_int, fin_w, out);
    }
}

// Round 9
// 277.547 us; speedup vs baseline: 1.4608x; 1.0291x over previous
//
#include <hip/hip_runtime.h>
#include <hip/hip_bf16.h>

// Problem constants
constexpr int Bsz = 2048;   // batch
constexpr int Iin = 6156;   // input features (= K = N of the big GEMM)
constexpr int IF  = 6159;   // I + O (fin_w row length)
constexpr int Kp  = 6208;   // K padded to multiple of 64 (97 * 64)
constexpr int NpW = 6272;   // w rows stored in ws (multiple of 128)
constexpr int NT  = Kp / 32;             // 194 K-tiles (BK=32)
constexpr int MT  = Bsz / 256;           // 8 M-tiles
constexpr int NTN = 25;                  // N-tiles of 256 (cols 6272..6399 virtual zeros)

typedef __attribute__((ext_vector_type(8))) short short8;
typedef __attribute__((ext_vector_type(4))) float f32x4;

#define AS1 __attribute__((address_space(1)))
#define AS3 __attribute__((address_space(3)))

__device__ __forceinline__ short f2bf(float f) {
    union { float f; unsigned u; } v; v.f = f;
    unsigned r = v.u + 0x7FFFu + ((v.u >> 16) & 1u);   // RNE
    return (short)(r >> 16);
}

__device__ __forceinline__ short8 pack8(float4 a, float4 b) {
    short8 r;
    r[0] = f2bf(a.x); r[1] = f2bf(a.y); r[2] = f2bf(a.z); r[3] = f2bf(a.w);
    r[4] = f2bf(b.x); r[5] = f2bf(b.y); r[6] = f2bf(b.z); r[7] = f2bf(b.w);
    return r;
}

__device__ __forceinline__ void stage_chunk(const short* src, const short* ldsbase) {
    __builtin_amdgcn_global_load_lds((const AS1 void*)src, (AS3 void*)ldsbase, 16, 0, 0);
}

// ---------------------------------------------------------------------------
// Kernel 1: linear path + bias; fully initializes d_out.
// ---------------------------------------------------------------------------
__global__ void linear_init_kernel(const float* __restrict__ x,
                                   const float* __restrict__ lin_w,
                                   const float* __restrict__ lin_b,
                                   const float* __restrict__ fin_w,
                                   const float* __restrict__ fin_b,
                                   float* __restrict__ out) {
    int wid  = threadIdx.x >> 6;
    int lane = threadIdx.x & 63;
    int b = blockIdx.x * 4 + wid;
    if (b >= Bsz) return;
    const float4* xr = (const float4*)(x + (size_t)b * Iin);
    const float4* w0 = (const float4*)(lin_w);
    const float4* w1 = (const float4*)(lin_w + Iin);
    const float4* w2 = (const float4*)(lin_w + 2 * Iin);
    float s0 = 0.f, s1 = 0.f, s2 = 0.f;
    for (int i = lane; i < Iin / 4; i += 64) {
        float4 xv = xr[i];
        float4 a0 = w0[i], a1 = w1[i], a2 = w2[i];
        s0 += xv.x * a0.x + xv.y * a0.y + xv.z * a0.z + xv.w * a0.w;
        s1 += xv.x * a1.x + xv.y * a1.y + xv.z * a1.z + xv.w * a1.w;
        s2 += xv.x * a2.x + xv.y * a2.y + xv.z * a2.z + xv.w * a2.w;
    }
    #pragma unroll
    for (int off = 1; off < 64; off <<= 1) {
        s0 += __shfl_xor(s0, off, 64);
        s1 += __shfl_xor(s1, off, 64);
        s2 += __shfl_xor(s2, off, 64);
    }
    if (lane == 0) {
        float l0 = s0 + lin_b[0], l1 = s1 + lin_b[1], l2 = s2 + lin_b[2];
        #pragma unroll
        for (int o = 0; o < 3; ++o) {
            out[b * 3 + o] = fin_b[o]
                + fin_w[(size_t)o * IF + 0] * l0
                + fin_w[(size_t)o * IF + 1] * l1
                + fin_w[(size_t)o * IF + 2] * l2;
        }
    }
}

// ---------------------------------------------------------------------------
// Kernel 2: f32 -> bf16 conversion, zero padding, + segment XOR swizzle for
// BK=32 rows: within each 4-slot (32-col) block, ws slot sub holds source
// segment sub ^ ((r>>1)&3).
// ---------------------------------------------------------------------------
__global__ void convert_kernel(const float* __restrict__ src,
                               short* __restrict__ dst,
                               int rows, int src_rows) {
    const int segs = Kp / 8;   // 776
    int total = rows * segs;
    for (int c = blockIdx.x * blockDim.x + threadIdx.x; c < total;
         c += gridDim.x * blockDim.x) {
        int r     = c / segs;
        int s_dst = c - r * segs;
        int blk   = s_dst >> 2;
        int sub   = s_dst & 3;
        int src_col = (blk << 5) + ((sub ^ ((r >> 1) & 3)) << 3);
        short8 st;
        if (r < src_rows && src_col + 8 <= Iin) {
            const float* s = src + (size_t)r * Iin + src_col;
            float4 f0 = *(const float4*)s;
            float4 f1 = *(const float4*)(s + 4);
            st = pack8(f0, f1);
        } else if (r < src_rows && src_col < Iin) {
            const float* s = src + (size_t)r * Iin + src_col;
            #pragma unroll
            for (int e = 0; e < 8; ++e) {
                float v = (src_col + e < Iin) ? s[e] : 0.f;
                st[e] = f2bf(v);
            }
        } else {
            #pragma unroll
            for (int e = 0; e < 8; ++e) st[e] = 0;
        }
        *(short8*)&dst[(size_t)r * Kp + (size_t)s_dst * 8] = st;
    }
}

// ---------------------------------------------------------------------------
// Kernel 3: 256x256 GEMM z = x @ w_int^T (bf16 MFMA) + interaction epilogue.
// 8 waves (2M x 4N), wave-tile 128x64 (M_rep=8, N_rep=4). BK=32.
// ALL fragment reads prefetched one section ahead, ISSUED UNDER the MFMA
// cluster (af x8 after first m-group, bf x4 after last) so the CU LDS queue
// drains while the matrix pipe runs. One barrier / one vmcnt / one lgkm per
// section. 4-slot LDS ring, stage-ahead-3, counted vmcnt(4).
// ---------------------------------------------------------------------------
__global__ __launch_bounds__(512, 2) void gemm_ov(
    const short* __restrict__ xb, const short* __restrict__ wb,
    const float* __restrict__ xf, const float* __restrict__ finw,
    float* __restrict__ out) {

    __shared__ short lsA[4][8192];   // [slot][256 rows x 32 cols]
    __shared__ short lsB[4][8192];
    __shared__ float part[256][3];

    const int tid  = threadIdx.x;
    const int lane = tid & 63;
    const int wid  = tid >> 6;       // 0..7
    const int wr   = wid >> 2;       // 0..1  (M half)
    const int wc   = wid & 3;        // 0..3  (N quarter)
    const int l15  = lane & 15;
    const int koff = (((lane >> 4) ^ ((lane >> 1) & 3)) << 3);  // swizzled k-slot

    // bijective XCD swizzle: 200 blocks = 8 XCDs x 25
    int swz = ((int)blockIdx.x & 7) * NTN + ((int)blockIdx.x >> 3);
    int tm = swz & 7;
    int tn = swz >> 3;
    int bm0 = tm << 8;
    int in0 = tn << 8;

    const int srow = lane >> 2;      // staging: row within 16-row wave chunk
    const int ssl  = lane & 3;       // staging: 16B slot within row
    const short* zptr = wb + 6176;   // 16 B of guaranteed zeros (row 0, cols>=Iin)

    f32x4 acc[8][4];
    #pragma unroll
    for (int m = 0; m < 8; ++m)
        #pragma unroll
        for (int n = 0; n < 4; ++n)
            acc[m][n] = (f32x4){0.f, 0.f, 0.f, 0.f};

    auto stageA = [&](int tk, int h) {
        int row = h * 128 + wid * 16 + srow;
        const short* src = xb + (size_t)(bm0 + row) * Kp + tk * 32 + ssl * 8;
        stage_chunk(src, &lsA[tk & 3][(h * 128 + wid * 16) * 32]);
    };
    auto stageB = [&](int tk, int h) {
        int row = h * 128 + wid * 16 + srow;
        int rg  = in0 + row;
        const short* src = (rg < NpW)
            ? wb + (size_t)rg * Kp + tk * 32 + ssl * 8 : zptr;
        stage_chunk(src, &lsB[tk & 3][(h * 128 + wid * 16) * 32]);
    };
    auto ldA = [&](int slot, int m) -> short8 {
        return *(const short8*)&lsA[slot][(wr * 128 + m * 16 + l15) * 32 + koff];
    };
    auto ldB = [&](int slot, int n) -> short8 {
        return *(const short8*)&lsB[slot][(wc * 64 + n * 16 + l15) * 32 + koff];
    };

    short8 afA[8], afB[8], bf[4];

    // prologue: stage tiles 0,1,2 (12 DMA); wait tile 0; read frags(0)
    stageA(0, 0); stageA(0, 1); stageB(0, 0); stageB(0, 1);
    stageA(1, 0); stageA(1, 1); stageB(1, 0); stageB(1, 1);
    stageA(2, 0); stageA(2, 1); stageB(2, 0); stageB(2, 1);
    asm volatile("s_waitcnt vmcnt(8)" ::: "memory");   // tile 0 landed
    __builtin_amdgcn_s_barrier();
    #pragma unroll
    for (int m = 0; m < 8; ++m) afA[m] = ldA(0, m);
    #pragma unroll
    for (int n = 0; n < 4; ++n) bf[n] = ldB(0, n);

// Section T: vmcnt(TW) -> barrier -> lgkm(0) -> MFMA m0 ->
//            [af(T+1)->NXT x8 ; stage(T+3) x4] -> MFMA m1..7 -> bf(T+1) x4.
// Steady state: outstanding at top = {T+1:4, T+2:4}=8; vmcnt(4) drains T+1,
// making the mid-section af/bf prefetch of slot (T+1)&3 RAW-safe.
#define SEC(T, CUR, NXT, TW, DO_PF, DO_ST)                                \
    {                                                                     \
        asm volatile("s_waitcnt " TW ::: "memory");                       \
        __builtin_amdgcn_s_barrier();                                     \
        asm volatile("s_waitcnt lgkmcnt(0)" ::: "memory");                \
        __builtin_amdgcn_sched_barrier(0);                                \
        __builtin_amdgcn_s_setprio(1);                                    \
        _Pragma("unroll")                                                 \
        for (int n = 0; n < 4; ++n)                                       \
            acc[0][n] = __builtin_amdgcn_mfma_f32_16x16x32_bf16(          \
                CUR[0], bf[n], acc[0][n], 0, 0, 0);                       \
        __builtin_amdgcn_s_setprio(0);                                    \
        __builtin_amdgcn_sched_barrier(0);                                \
        if (DO_PF) {                                                      \
            const int _ns = ((T) + 1) & 3;                                \
            _Pragma("unroll")                                             \
            for (int m = 0; m < 8; ++m) NXT[m] = ldA(_ns, m);             \
        }                                                                 \
        __builtin_amdgcn_sched_barrier(0);                                \
        if (DO_ST) {                                                      \
            stageA((T) + 3, 0); stageA((T) + 3, 1);                       \
            stageB((T) + 3, 0); stageB((T) + 3, 1);                       \
        }                                                                 \
        __builtin_amdgcn_sched_barrier(0);                                \
        __builtin_amdgcn_s_setprio(1);                                    \
        _Pragma("unroll")                                                 \
        for (int m = 1; m < 8; ++m)                                       \
            _Pragma("unroll")                                             \
            for (int n = 0; n < 4; ++n)                                   \
                acc[m][n] = __builtin_amdgcn_mfma_f32_16x16x32_bf16(      \
                    CUR[m], bf[n], acc[m][n], 0, 0, 0);                   \
        __builtin_amdgcn_s_setprio(0);                                    \
        __builtin_amdgcn_sched_barrier(0);                                \
        if (DO_PF) {                                                      \
            const int _nb = ((T) + 1) & 3;                                \
            _Pragma("unroll")                                             \
            for (int n = 0; n < 4; ++n) bf[n] = ldB(_nb, n);              \
        }                                                                 \
        __builtin_amdgcn_sched_barrier(0);                                \
    }

    for (int i = 0; i < 95; ++i) {          // t = 0..189 (all full sections)
        int t = 2 * i;
        SEC(t,     afA, afB, "vmcnt(4)", true, true);
        SEC(t + 1, afB, afA, "vmcnt(4)", true, true);
    }
    SEC(190, afA, afB, "vmcnt(4)", true,  true);    // stages tile 193 (last)
    SEC(191, afB, afA, "vmcnt(4)", true,  false);
    SEC(192, afA, afB, "vmcnt(0)", true,  false);   // tile 193 landed
    SEC(193, afB, afA, "vmcnt(0)", false, false);
#undef SEC

    // ---- epilogue: out[b,o] += sum_gi finw[o,3+gi] * x[b,gi] * z[b,gi]
    __syncthreads();
    for (int t = tid; t < 768; t += 512) ((float*)part)[t] = 0.f;
    __syncthreads();

    int q4 = lane >> 4;
    #pragma unroll
    for (int m = 0; m < 8; ++m) {
        #pragma unroll
        for (int r = 0; r < 4; ++r) {
            int lr = wr * 128 + m * 16 + q4 * 4 + r;   // 0..255
            int bg = bm0 + lr;
            float s0 = 0.f, s1 = 0.f, s2 = 0.f;
            #pragma unroll
            for (int n = 0; n < 4; ++n) {
                int gi = in0 + wc * 64 + n * 16 + l15;
                if (gi < Iin) {
                    float inter = acc[m][n][r] * xf[(size_t)bg * Iin + gi];
                    s0 += inter * finw[(size_t)0 * IF + 3 + gi];
                    s1 += inter * finw[(size_t)1 * IF + 3 + gi];
                    s2 += inter * finw[(size_t)2 * IF + 3 + gi];
                }
            }
            #pragma unroll
            for (int off = 1; off < 16; off <<= 1) {
                s0 += __shfl_xor(s0, off, 64);
                s1 += __shfl_xor(s1, off, 64);
                s2 += __shfl_xor(s2, off, 64);
            }
            if (l15 == 0) {
                atomicAdd(&part[lr][0], s0);
                atomicAdd(&part[lr][1], s1);
                atomicAdd(&part[lr][2], s2);
            }
        }
    }
    __syncthreads();
    for (int t = tid; t < 768; t += 512) {
        int lr = t / 3, o = t - lr * 3;
        atomicAdd(&out[(size_t)(bm0 + lr) * 3 + o], part[lr][o]);
    }
}

// ---------------------------------------------------------------------------
// Fallback (no workspace): self-staged 2-barrier kernel (mask-7 swizzle).
// ---------------------------------------------------------------------------
__global__ __launch_bounds__(256) void gemm_fallback(
    const float* __restrict__ xf, const float* __restrict__ wf,
    const float* __restrict__ finw, float* __restrict__ out) {

    __shared__ short lsA[128 * 64];
    __shared__ short lsB[128 * 64];
    __shared__ float part[128][3];

    int tid  = threadIdx.x;
    int lane = tid & 63;
    int wid  = tid >> 6;
    int wm   = wid & 1;
    int wn   = wid >> 1;

    int ntiles = (Bsz / 128) * (NpW / 128);
    int tile = (blockIdx.x & 7) * (ntiles >> 3) + (blockIdx.x >> 3);
    int tm = tile & 15;
    int tn = tile >> 4;
    int bm0 = tm << 7;
    int in0 = tn << 7;

    f32x4 acc[4][4];
    #pragma unroll
    for (int m = 0; m < 4; ++m)
        #pragma unroll
        for (int n = 0; n < 4; ++n)
            acc[m][n] = (f32x4){0.f, 0.f, 0.f, 0.f};

    for (int k0 = 0; k0 < Kp; k0 += 64) {
        #pragma unroll
        for (int it = 0; it < 4; ++it) {
            int idx = it * 256 + tid;
            int r   = idx >> 3;
            int seg = idx & 7;
            int kc  = k0 + seg * 8;
            int sd  = (seg ^ (r & 7)) << 3;
            {
                const float* s = xf + (size_t)(bm0 + r) * Iin + kc;
                short8 st;
                if (kc + 8 <= Iin) {
                    float4 f0 = *(const float4*)s;
                    float4 f1 = *(const float4*)(s + 4);
                    st = pack8(f0, f1);
                } else {
                    #pragma unroll
                    for (int e = 0; e < 8; ++e) {
                        float v = (kc + e < Iin) ? s[e] : 0.f;
                        st[e] = f2bf(v);
                    }
                }
                *(short8*)&lsA[r * 64 + sd] = st;
            }
            {
                int grow = in0 + r;
                short8 st;
                if (grow < Iin && kc + 8 <= Iin) {
                    const float* s = wf + (size_t)grow * Iin + kc;
                    float4 f0 = *(const float4*)s;
                    float4 f1 = *(const float4*)(s + 4);
                    st = pack8(f0, f1);
                } else if (grow < Iin) {
                    const float* s = wf + (size_t)grow * Iin + kc;
                    #pragma unroll
                    for (int e = 0; e < 8; ++e) {
                        float v = (kc + e < Iin) ? s[e] : 0.f;
                        st[e] = f2bf(v);
                    }
                } else {
                    #pragma unroll
                    for (int e = 0; e < 8; ++e) st[e] = 0;
                }
                *(short8*)&lsB[r * 64 + sd] = st;
            }
        }
        __syncthreads();

        #pragma unroll
        for (int kk = 0; kk < 2; ++kk) {
            int q = (kk << 2) + (lane >> 4);
            short8 af[4], bfr[4];
            #pragma unroll
            for (int m = 0; m < 4; ++m) {
                int R = wm * 64 + m * 16 + (lane & 15);
                af[m] = *(const short8*)&lsA[R * 64 + ((q ^ (R & 7)) << 3)];
            }
            #pragma unroll
            for (int n = 0; n < 4; ++n) {
                int R = wn * 64 + n * 16 + (lane & 15);
                bfr[n] = *(const short8*)&lsB[R * 64 + ((q ^ (R & 7)) << 3)];
            }
            #pragma unroll
            for (int m = 0; m < 4; ++m)
                #pragma unroll
                for (int n = 0; n < 4; ++n)
                    acc[m][n] = __builtin_amdgcn_mfma_f32_16x16x32_bf16(
                        af[m], bfr[n], acc[m][n], 0, 0, 0);
        }
        __syncthreads();
    }

    for (int t = tid; t < 384; t += 256) ((float*)part)[t] = 0.f;
    __syncthreads();

    #pragma unroll
    for (int m = 0; m < 4; ++m) {
        int rowbase = bm0 + wm * 64 + m * 16 + ((lane >> 4) << 2);
        #pragma unroll
        for (int r = 0; r < 4; ++r) {
            int b = rowbase + r;
            float s0 = 0.f, s1 = 0.f, s2 = 0.f;
            #pragma unroll
            for (int n = 0; n < 4; ++n) {
                int gi = in0 + wn * 64 + n * 16 + (lane & 15);
                if (gi < Iin) {
                    float inter = acc[m][n][r] * xf[(size_t)b * Iin + gi];
                    s0 += inter * finw[(size_t)0 * IF + 3 + gi];
                    s1 += inter * finw[(size_t)1 * IF + 3 + gi];
                    s2 += inter * finw[(size_t)2 * IF + 3 + gi];
                }
            }
            #pragma unroll
            for (int off = 1; off < 16; off <<= 1) {
                s0 += __shfl_xor(s0, off, 64);
                s1 += __shfl_xor(s1, off, 64);
                s2 += __shfl_xor(s2, off, 64);
            }
            if ((lane & 15) == 0) {
                int lr = b - bm0;
                atomicAdd(&part[lr][0], s0);
                atomicAdd(&part[lr][1], s1);
                atomicAdd(&part[lr][2], s2);
            }
        }
    }
    __syncthreads();
    for (int t = tid; t < 384; t += 256) {
        int lr = t / 3, o = t - lr * 3;
        atomicAdd(&out[(size_t)(bm0 + lr) * 3 + o], part[lr][o]);
    }
}

// ---------------------------------------------------------------------------
extern "C" void kernel_launch(void* const* d_in, const int* in_sizes, int n_in,
                              void* d_out, int out_size, void* d_ws, size_t ws_size,
                              hipStream_t stream) {
    const float* x     = (const float*)d_in[0];
    const float* lin_w = (const float*)d_in[1];
    const float* lin_b = (const float*)d_in[2];
    const float* w_int = (const float*)d_in[3];
    const float* fin_w = (const float*)d_in[4];
    const float* fin_b = (const float*)d_in[5];
    float* out = (float*)d_out;

    linear_init_kernel<<<Bsz / 4, 256, 0, stream>>>(x, lin_w, lin_b, fin_w, fin_b, out);

    const size_t xb_elems = (size_t)Bsz * Kp;    // 12,713,984
    const size_t wb_elems = (size_t)NpW * Kp;    // 38,936,576
    const size_t need = (xb_elems + wb_elems) * sizeof(short);   // 103.3 MB

    if (ws_size >= need) {
        short* xb = (short*)d_ws;
        short* wb = xb + xb_elems;
        convert_kernel<<<2048, 256, 0, stream>>>(x, xb, Bsz, Bsz);
        convert_kernel<<<2048, 256, 0, stream>>>(w_int, wb, NpW, Iin);
        gemm_ov<<<MT * NTN, 512, 0, stream>>>(xb, wb, x, fin_w, out);
    } else {
        const int ntiles = (Bsz / 128) * (NpW / 128);
        gemm_fallback<<<ntiles, 256, 0, stream>>>(x, w_int, fin_w, out);
    }
}

// Round 10
// 175.667 us; speedup vs baseline: 2.3080x; 1.5800x over previous
//
#include <hip/hip_runtime.h>
#include <hip/hip_bf16.h>

// Problem constants
constexpr int Bsz = 2048;   // batch
constexpr int Iin = 6156;   // input features (= K = N of the big GEMM)
constexpr int IF  = 6159;   // I + O (fin_w row length)
constexpr int Kp  = 6208;   // K padded to multiple of 64 (97 * 64); i8: bytes/row
constexpr int NpW = 6400;   // w rows stored in ws (25 * 256, guard-free)
constexpr int NTI = Kp / 64;             // 97 K-sections (BK=64 i8 elems)
constexpr int MT  = Bsz / 256;           // 8 M-tiles
constexpr int NTN = 25;                  // N-tiles of 256

typedef __attribute__((ext_vector_type(8))) short short8;
typedef __attribute__((ext_vector_type(4))) float f32x4;
typedef __attribute__((ext_vector_type(4))) int   i32x4;

#define AS1 __attribute__((address_space(1)))
#define AS3 __attribute__((address_space(3)))

__device__ __forceinline__ short f2bf(float f) {
    union { float f; unsigned u; } v; v.f = f;
    unsigned r = v.u + 0x7FFFu + ((v.u >> 16) & 1u);   // RNE
    return (short)(r >> 16);
}

__device__ __forceinline__ short8 pack8(float4 a, float4 b) {
    short8 r;
    r[0] = f2bf(a.x); r[1] = f2bf(a.y); r[2] = f2bf(a.z); r[3] = f2bf(a.w);
    r[4] = f2bf(b.x); r[5] = f2bf(b.y); r[6] = f2bf(b.z); r[7] = f2bf(b.w);
    return r;
}

__device__ __forceinline__ void stage_chunk(const void* src, const void* ldsbase) {
    __builtin_amdgcn_global_load_lds((const AS1 void*)src, (AS3 void*)ldsbase, 16, 0, 0);
}

// ---------------------------------------------------------------------------
// Kernel 1: linear path + bias; fully initializes d_out.
// ---------------------------------------------------------------------------
__global__ void linear_init_kernel(const float* __restrict__ x,
                                   const float* __restrict__ lin_w,
                                   const float* __restrict__ lin_b,
                                   const float* __restrict__ fin_w,
                                   const float* __restrict__ fin_b,
                                   float* __restrict__ out) {
    int wid  = threadIdx.x >> 6;
    int lane = threadIdx.x & 63;
    int b = blockIdx.x * 4 + wid;
    if (b >= Bsz) return;
    const float4* xr = (const float4*)(x + (size_t)b * Iin);
    const float4* w0 = (const float4*)(lin_w);
    const float4* w1 = (const float4*)(lin_w + Iin);
    const float4* w2 = (const float4*)(lin_w + 2 * Iin);
    float s0 = 0.f, s1 = 0.f, s2 = 0.f;
    for (int i = lane; i < Iin / 4; i += 64) {
        float4 xv = xr[i];
        float4 a0 = w0[i], a1 = w1[i], a2 = w2[i];
        s0 += xv.x * a0.x + xv.y * a0.y + xv.z * a0.z + xv.w * a0.w;
        s1 += xv.x * a1.x + xv.y * a1.y + xv.z * a1.z + xv.w * a1.w;
        s2 += xv.x * a2.x + xv.y * a2.y + xv.z * a2.z + xv.w * a2.w;
    }
    #pragma unroll
    for (int off = 1; off < 64; off <<= 1) {
        s0 += __shfl_xor(s0, off, 64);
        s1 += __shfl_xor(s1, off, 64);
        s2 += __shfl_xor(s2, off, 64);
    }
    if (lane == 0) {
        float l0 = s0 + lin_b[0], l1 = s1 + lin_b[1], l2 = s2 + lin_b[2];
        #pragma unroll
        for (int o = 0; o < 3; ++o) {
            out[b * 3 + o] = fin_b[o]
                + fin_w[(size_t)o * IF + 0] * l0
                + fin_w[(size_t)o * IF + 1] * l1
                + fin_w[(size_t)o * IF + 2] * l2;
        }
    }
}

// ---------------------------------------------------------------------------
// Kernel 2: per-row absmax int8 quantization with K-pad and the 16B-granule
// XOR swizzle (dest slot sub within each 64-col block holds source cols
// blk*64 + (sub^((row>>1)&3))*16). One block per row; row staged in LDS.
// Rows >= src_rows: zeros, scale 0.
// ---------------------------------------------------------------------------
__global__ __launch_bounds__(256) void quant_kernel(
    const float* __restrict__ src, signed char* __restrict__ dst,
    float* __restrict__ scales, int src_rows) {
    __shared__ float rowbuf[Kp];
    __shared__ float red[4];
    int row = blockIdx.x;
    int t   = threadIdx.x;
    float amax = 0.f;
    if (row < src_rows) {
        const float4* s = (const float4*)(src + (size_t)row * Iin);
        for (int i = t; i < Iin / 4; i += 256) {      // 1539 float4s
            float4 v = s[i];
            ((float4*)rowbuf)[i] = v;
            amax = fmaxf(amax, fmaxf(fmaxf(fabsf(v.x), fabsf(v.y)),
                                     fmaxf(fabsf(v.z), fabsf(v.w))));
        }
        for (int i = Iin + t; i < Kp; i += 256) rowbuf[i] = 0.f;
    } else {
        for (int i = t; i < Kp; i += 256) rowbuf[i] = 0.f;
    }
    #pragma unroll
    for (int off = 1; off < 64; off <<= 1)
        amax = fmaxf(amax, __shfl_xor(amax, off, 64));
    if ((t & 63) == 0) red[t >> 6] = amax;
    __syncthreads();
    float am = fmaxf(fmaxf(red[0], red[1]), fmaxf(red[2], red[3]));
    float rs = (am > 0.f) ? 127.f / am : 0.f;
    if (t == 0) scales[row] = (am > 0.f) ? am / 127.f : 0.f;

    int xorv = (row >> 1) & 3;
    for (int p = t; p < Kp / 16; p += 256) {          // 388 granules
        int blk = p >> 2, sub = p & 3;
        int sc  = (blk << 6) + ((sub ^ xorv) << 4);   // source col base (16 elems)
        i32x4 pk;
        #pragma unroll
        for (int j = 0; j < 4; ++j) {
            unsigned u = 0;
            #pragma unroll
            for (int e = 0; e < 4; ++e) {
                float v = rowbuf[sc + j * 4 + e] * rs;
                int q = (int)rintf(v);
                q = q > 127 ? 127 : (q < -127 ? -127 : q);
                u |= ((unsigned)(q & 255)) << (8 * e);
            }
            pk[j] = (int)u;
        }
        *(i32x4*)(dst + (size_t)row * Kp + (size_t)p * 16) = pk;
    }
}

// ---------------------------------------------------------------------------
// Kernel 3: 256x256 int8 GEMM z = x @ w^T (mfma_i32_16x16x64_i8) + epilogue.
// 8 waves (2M x 4N), wave-tile 128x64 (M_rep=8, N_rep=4). BK=64 i8.
// R6-proven schedule, 97 sections: per section {vmcnt(4); barrier; bf(t) x4;
// prefetch af(t+1) x8; stage(t+3) x4 DMA; lgkm(8); setprio 32 MFMA}.
// 4-slot LDS ring (16KB/slot/matrix), byte layout identical to the bf16
// version (64B rows, 16B granules, same XOR swizzle -> zero conflicts).
// Epilogue dequantizes: z = sx[b]*sw[j]*acc.
// ---------------------------------------------------------------------------
__global__ __launch_bounds__(512, 2) void gemm_i8(
    const signed char* __restrict__ xq, const signed char* __restrict__ wq,
    const float* __restrict__ sx, const float* __restrict__ sw,
    const float* __restrict__ xf, const float* __restrict__ finw,
    float* __restrict__ out) {

    __shared__ signed char lsA[4][16384];   // [slot][256 rows x 64 B]
    __shared__ signed char lsB[4][16384];
    __shared__ float part[256][3];

    const int tid  = threadIdx.x;
    const int lane = tid & 63;
    const int wid  = tid >> 6;       // 0..7
    const int wr   = wid >> 2;       // 0..1  (M half)
    const int wc   = wid & 3;        // 0..3  (N quarter)
    const int l15  = lane & 15;
    const int koff = (((lane >> 4) ^ ((lane >> 1) & 3)) << 4);  // swizzled 16B slot

    // bijective XCD swizzle: 200 blocks = 8 XCDs x 25
    int swz = ((int)blockIdx.x & 7) * NTN + ((int)blockIdx.x >> 3);
    int tm = swz & 7;
    int tn = swz >> 3;
    int bm0 = tm << 8;
    int in0 = tn << 8;

    i32x4 acc[8][4];
    #pragma unroll
    for (int m = 0; m < 8; ++m)
        #pragma unroll
        for (int n = 0; n < 4; ++n)
            acc[m][n] = (i32x4){0, 0, 0, 0};

    // staging: half h (rows h*128..+127): 512 granules; thread covers one.
    auto stageA = [&](int tk, int h) {
        int idx = h * 512 + tid;
        int row = idx >> 2, sub = idx & 3;
        const signed char* src = xq + (size_t)(bm0 + row) * Kp + tk * 64 + sub * 16;
        stage_chunk(src, &lsA[tk & 3][(size_t)idx * 16]);
    };
    auto stageB = [&](int tk, int h) {
        int idx = h * 512 + tid;
        int row = idx >> 2, sub = idx & 3;
        const signed char* src = wq + (size_t)(in0 + row) * Kp + tk * 64 + sub * 16;
        stage_chunk(src, &lsB[tk & 3][(size_t)idx * 16]);
    };
    auto ldA = [&](int slot, int m) -> i32x4 {
        int row = wr * 128 + m * 16 + l15;
        return *(const i32x4*)&lsA[slot][row * 64 + koff];
    };
    auto ldB = [&](int slot, int n) -> i32x4 {
        int row = wc * 64 + n * 16 + l15;
        return *(const i32x4*)&lsB[slot][row * 64 + koff];
    };

    i32x4 afA[8], afB[8], bf[4];

    // prologue: stage tiles 0,1,2 (12 DMA/thread); wait tile 0; read afA(0)
    stageA(0, 0); stageA(0, 1); stageB(0, 0); stageB(0, 1);
    stageA(1, 0); stageA(1, 1); stageB(1, 0); stageB(1, 1);
    stageA(2, 0); stageA(2, 1); stageB(2, 0); stageB(2, 1);
    asm volatile("s_waitcnt vmcnt(8)" ::: "memory");   // tile 0 landed
    __builtin_amdgcn_s_barrier();
    #pragma unroll
    for (int m = 0; m < 8; ++m) afA[m] = ldA(0, m);

// Section T (R6 scheme): top vmcnt -> barrier -> bf(T) x4 -> af(T+1)->NXT x8
// -> stage(T+3) x4 -> lgkm(8 if PF else 0) -> 32 MFMA on CUR.
// lgkm at wait point = CUR's 8 (prev section) + bf 4 + NXT 8 = 20;
// lgkm(8) drains CUR+bf, leaves NXT in flight under the MFMA cluster.
#define SEC(T, CUR, NXT, TW, DO_PF, DO_ST)                                \
    {                                                                     \
        asm volatile("s_waitcnt " TW ::: "memory");                       \
        __builtin_amdgcn_s_barrier();                                     \
        const int _sl = (T) & 3;                                          \
        _Pragma("unroll")                                                 \
        for (int n = 0; n < 4; ++n) bf[n] = ldB(_sl, n);                  \
        __builtin_amdgcn_sched_barrier(0);                                \
        if (DO_PF) {                                                      \
            const int _ns = ((T) + 1) & 3;                                \
            _Pragma("unroll")                                             \
            for (int m = 0; m < 8; ++m) NXT[m] = ldA(_ns, m);             \
        }                                                                 \
        __builtin_amdgcn_sched_barrier(0);                                \
        if (DO_ST) {                                                      \
            stageA((T) + 3, 0); stageA((T) + 3, 1);                       \
            stageB((T) + 3, 0); stageB((T) + 3, 1);                       \
        }                                                                 \
        __builtin_amdgcn_sched_barrier(0);                                \
        if (DO_PF) { asm volatile("s_waitcnt lgkmcnt(8)" ::: "memory"); } \
        else       { asm volatile("s_waitcnt lgkmcnt(0)" ::: "memory"); } \
        __builtin_amdgcn_sched_barrier(0);                                \
        __builtin_amdgcn_s_setprio(1);                                    \
        _Pragma("unroll")                                                 \
        for (int m = 0; m < 8; ++m)                                       \
            _Pragma("unroll")                                             \
            for (int n = 0; n < 4; ++n)                                   \
                acc[m][n] = __builtin_amdgcn_mfma_i32_16x16x64_i8(        \
                    CUR[m], bf[n], acc[m][n], 0, 0, 0);                   \
        __builtin_amdgcn_s_setprio(0);                                    \
        __builtin_amdgcn_sched_barrier(0);                                \
    }

    for (int i = 0; i < 47; ++i) {          // sections 0..93
        int t = 2 * i;
        SEC(t,     afA, afB, "vmcnt(4)", true, true);
        SEC(t + 1, afB, afA, "vmcnt(4)", true, true);
    }
    SEC(94, afA, afB, "vmcnt(4)", true,  false);   // tile 95 landed for PF
    SEC(95, afB, afA, "vmcnt(0)", true,  false);   // tile 96 landed for PF
    SEC(96, afA, afB, "vmcnt(0)", false, false);
#undef SEC

    // ---- epilogue: out[b,o] += sum_gi finw[o,3+gi] * x[b,gi] * z[b,gi]
    //      z[b,gi] = sx[b] * sw[gi] * acc
    __syncthreads();
    for (int t = tid; t < 768; t += 512) ((float*)part)[t] = 0.f;
    __syncthreads();

    int q4 = lane >> 4;
    #pragma unroll
    for (int m = 0; m < 8; ++m) {
        #pragma unroll
        for (int r = 0; r < 4; ++r) {
            int lr = wr * 128 + m * 16 + q4 * 4 + r;   // 0..255
            int bg = bm0 + lr;
            float sxv = sx[bg];
            float s0 = 0.f, s1 = 0.f, s2 = 0.f;
            #pragma unroll
            for (int n = 0; n < 4; ++n) {
                int gi = in0 + wc * 64 + n * 16 + l15;
                if (gi < Iin) {
                    float z = (float)acc[m][n][r] * sxv * sw[gi];
                    float inter = z * xf[(size_t)bg * Iin + gi];
                    s0 += inter * finw[(size_t)0 * IF + 3 + gi];
                    s1 += inter * finw[(size_t)1 * IF + 3 + gi];
                    s2 += inter * finw[(size_t)2 * IF + 3 + gi];
                }
            }
            #pragma unroll
            for (int off = 1; off < 16; off <<= 1) {
                s0 += __shfl_xor(s0, off, 64);
                s1 += __shfl_xor(s1, off, 64);
                s2 += __shfl_xor(s2, off, 64);
            }
            if (l15 == 0) {
                atomicAdd(&part[lr][0], s0);
                atomicAdd(&part[lr][1], s1);
                atomicAdd(&part[lr][2], s2);
            }
        }
    }
    __syncthreads();
    for (int t = tid; t < 768; t += 512) {
        int lr = t / 3, o = t - lr * 3;
        atomicAdd(&out[(size_t)(bm0 + lr) * 3 + o], part[lr][o]);
    }
}

// ---------------------------------------------------------------------------
// Fallback (no workspace): self-staged bf16 2-barrier kernel (mask-7 swizzle).
// ---------------------------------------------------------------------------
__global__ __launch_bounds__(256) void gemm_fallback(
    const float* __restrict__ xf, const float* __restrict__ wf,
    const float* __restrict__ finw, float* __restrict__ out) {

    __shared__ short lsA[128 * 64];
    __shared__ short lsB[128 * 64];
    __shared__ float part[128][3];

    int tid  = threadIdx.x;
    int lane = tid & 63;
    int wid  = tid >> 6;
    int wm   = wid & 1;
    int wn   = wid >> 1;

    int ntiles = (Bsz / 128) * (6272 / 128);
    int tile = (blockIdx.x & 7) * (ntiles >> 3) + (blockIdx.x >> 3);
    int tm = tile & 15;
    int tn = tile >> 4;
    int bm0 = tm << 7;
    int in0 = tn << 7;

    f32x4 acc[4][4];
    #pragma unroll
    for (int m = 0; m < 4; ++m)
        #pragma unroll
        for (int n = 0; n < 4; ++n)
            acc[m][n] = (f32x4){0.f, 0.f, 0.f, 0.f};

    for (int k0 = 0; k0 < Kp; k0 += 64) {
        #pragma unroll
        for (int it = 0; it < 4; ++it) {
            int idx = it * 256 + tid;
            int r   = idx >> 3;
            int seg = idx & 7;
            int kc  = k0 + seg * 8;
            int sd  = (seg ^ (r & 7)) << 3;
            {
                const float* s = xf + (size_t)(bm0 + r) * Iin + kc;
                short8 st;
                if (kc + 8 <= Iin) {
                    float4 f0 = *(const float4*)s;
                    float4 f1 = *(const float4*)(s + 4);
                    st = pack8(f0, f1);
                } else {
                    #pragma unroll
                    for (int e = 0; e < 8; ++e) {
                        float v = (kc + e < Iin) ? s[e] : 0.f;
                        st[e] = f2bf(v);
                    }
                }
                *(short8*)&lsA[r * 64 + sd] = st;
            }
            {
                int grow = in0 + r;
                short8 st;
                if (grow < Iin && kc + 8 <= Iin) {
                    const float* s = wf + (size_t)grow * Iin + kc;
                    float4 f0 = *(const float4*)s;
                    float4 f1 = *(const float4*)(s + 4);
                    st = pack8(f0, f1);
                } else if (grow < Iin) {
                    const float* s = wf + (size_t)grow * Iin + kc;
                    #pragma unroll
                    for (int e = 0; e < 8; ++e) {
                        float v = (kc + e < Iin) ? s[e] : 0.f;
                        st[e] = f2bf(v);
                    }
                } else {
                    #pragma unroll
                    for (int e = 0; e < 8; ++e) st[e] = 0;
                }
                *(short8*)&lsB[r * 64 + sd] = st;
            }
        }
        __syncthreads();

        #pragma unroll
        for (int kk = 0; kk < 2; ++kk) {
            int q = (kk << 2) + (lane >> 4);
            short8 af[4], bfr[4];
            #pragma unroll
            for (int m = 0; m < 4; ++m) {
                int R = wm * 64 + m * 16 + (lane & 15);
                af[m] = *(const short8*)&lsA[R * 64 + ((q ^ (R & 7)) << 3)];
            }
            #pragma unroll
            for (int n = 0; n < 4; ++n) {
                int R = wn * 64 + n * 16 + (lane & 15);
                bfr[n] = *(const short8*)&lsB[R * 64 + ((q ^ (R & 7)) << 3)];
            }
            #pragma unroll
            for (int m = 0; m < 4; ++m)
                #pragma unroll
                for (int n = 0; n < 4; ++n)
                    acc[m][n] = __builtin_amdgcn_mfma_f32_16x16x32_bf16(
                        af[m], bfr[n], acc[m][n], 0, 0, 0);
        }
        __syncthreads();
    }

    for (int t = tid; t < 384; t += 256) ((float*)part)[t] = 0.f;
    __syncthreads();

    #pragma unroll
    for (int m = 0; m < 4; ++m) {
        int rowbase = bm0 + wm * 64 + m * 16 + ((lane >> 4) << 2);
        #pragma unroll
        for (int r = 0; r < 4; ++r) {
            int b = rowbase + r;
            float s0 = 0.f, s1 = 0.f, s2 = 0.f;
            #pragma unroll
            for (int n = 0; n < 4; ++n) {
                int gi = in0 + wn * 64 + n * 16 + (lane & 15);
                if (gi < Iin) {
                    float inter = acc[m][n][r] * xf[(size_t)b * Iin + gi];
                    s0 += inter * finw[(size_t)0 * IF + 3 + gi];
                    s1 += inter * finw[(size_t)1 * IF + 3 + gi];
                    s2 += inter * finw[(size_t)2 * IF + 3 + gi];
                }
            }
            #pragma unroll
            for (int off = 1; off < 16; off <<= 1) {
                s0 += __shfl_xor(s0, off, 64);
                s1 += __shfl_xor(s1, off, 64);
                s2 += __shfl_xor(s2, off, 64);
            }
            if ((lane & 15) == 0) {
                int lr = b - bm0;
                atomicAdd(&part[lr][0], s0);
                atomicAdd(&part[lr][1], s1);
                atomicAdd(&part[lr][2], s2);
            }
        }
    }
    __syncthreads();
    for (int t = tid; t < 384; t += 256) {
        int lr = t / 3, o = t - lr * 3;
        atomicAdd(&out[(size_t)(bm0 + lr) * 3 + o], part[lr][o]);
    }
}

// ---------------------------------------------------------------------------
extern "C" void kernel_launch(void* const* d_in, const int* in_sizes, int n_in,
                              void* d_out, int out_size, void* d_ws, size_t ws_size,
                              hipStream_t stream) {
    const float* x     = (const float*)d_in[0];
    const float* lin_w = (const float*)d_in[1];
    const float* lin_b = (const float*)d_in[2];
    const float* w_int = (const float*)d_in[3];
    const float* fin_w = (const float*)d_in[4];
    const float* fin_b = (const float*)d_in[5];
    float* out = (float*)d_out;

    linear_init_kernel<<<Bsz / 4, 256, 0, stream>>>(x, lin_w, lin_b, fin_w, fin_b, out);

    const size_t xq_bytes = (size_t)Bsz * Kp;          // 12,713,984
    const size_t wq_bytes = (size_t)NpW * Kp;          // 39,731,200
    const size_t sx_off   = xq_bytes + wq_bytes;       // 52,445,184 (16-aligned)
    const size_t need = sx_off + (Bsz + NpW) * sizeof(float);

    if (ws_size >= need) {
        signed char* xq = (signed char*)d_ws;
        signed char* wq = xq + xq_bytes;
        float* sxp = (float*)((char*)d_ws + sx_off);
        float* swp = sxp + Bsz;
        quant_kernel<<<Bsz, 256, 0, stream>>>(x, xq, sxp, Bsz);
        quant_kernel<<<NpW, 256, 0, stream>>>(w_int, wq, swp, Iin);
        gemm_i8<<<MT * NTN, 512, 0, stream>>>(xq, wq, sxp, swp, x, fin_w, out);
    } else {
        const int ntiles = (Bsz / 128) * (6272 / 128);
        gemm_fallback<<<ntiles, 256, 0, stream>>>(x, w_int, fin_w, out);
    }
}